// Round 2
// baseline (298.144 us; speedup 1.0000x reference)
//
#include <hip/hip_runtime.h>
#include <stdint.h>

// ---------------------------------------------------------------------------
// GCN block: 3 x [ h = leaky_relu(in @ W);  out = adj@h + h ]   (I folded OUT)
// B=64, N=4096, D=16.  GEMM M=4096 x C=1024 x K=4096 in FP8 e4m3, fp32 accum,
// MX-scaled mfma_scale_16x16x128 with unit scales (2.26x fp8 pipe rate).
// Round 8: r7 gemm was bound by LDS port (96 KB/CU-iter) + unoverlapped
// staging drain (vmcnt(0) between barriers = full HBM latency per iter).
//  - B operand now loaded DIRECT from L2 into registers (hb8 = 4 MB, hot;
//    same bytes the swizzled LDS read produced -> bit-identical result).
//  - A staging double-buffered in the freed LDS: stage(it+1) issued after
//    the barrier, drained at the NEXT barrier ~1100 cyc later (hidden).
//    One barrier/iter.  LDS 48 KB/CU-iter (768 cyc) < MFMA 1106 cyc floor.
// ws: adj8 16MB | hb8 4MB | h_nc 8MB | p0 8MB | p1 8MB = 44MB
// ---------------------------------------------------------------------------

typedef float  f32x4  __attribute__((ext_vector_type(4)));
typedef unsigned short ushort8 __attribute__((ext_vector_type(8)));
typedef int    i32x4  __attribute__((ext_vector_type(4)));
typedef int    i32x8  __attribute__((ext_vector_type(8)));

typedef __attribute__((address_space(1))) void* as1p;
typedef __attribute__((address_space(3))) void* as3p;
#define GLOAD_LDS16(G, L) \
  __builtin_amdgcn_global_load_lds((as1p)(G), (as3p)(L), 16, 0, 0)

#define P_ELEMS 4194304       // elems per partial buffer (4096*1024)
#define ADJ_SCALE 4096.0f
#define ADJ_DESCALE (1.0f / 4096.0f)
#define SCALE_ONE 0x7f7f7f7f  // e8m0 exponent 127 = 2^0 = 1.0 in every byte

__device__ __forceinline__ unsigned short f2bf(float f) {
  unsigned u = __float_as_uint(f);
  u += 0x7fffu + ((u >> 16) & 1u);  // RNE
  return (unsigned short)(u >> 16);
}
__device__ __forceinline__ float bf2f(unsigned short u) {
  return __uint_as_float(((unsigned)u) << 16);
}
// pack 4 fp32 -> 4 fp8 e4m3 bytes (RNE, saturating)
__device__ __forceinline__ int pk4_fp8(float a, float b, float c, float d) {
  int v = __builtin_amdgcn_cvt_pk_fp8_f32(a, b, 0, false);   // bytes 0,1
  v = __builtin_amdgcn_cvt_pk_fp8_f32(c, d, v, true);        // bytes 2,3
  return v;
}

// ---------------------------------------------------------------------------
// prep: role-split fusion of two independent memory-bound kernels.
//   bid <  1024 : layer-0 linear  h0 = leaky(x @ W0), tile 64n x 64c
//   bid >= 1024 : adj8 = e4m3(adj * 4096), 1 thread = 16 elements
// ---------------------------------------------------------------------------
__global__ void prep(const float* __restrict__ adj,
                     unsigned char* __restrict__ a8,
                     const float* __restrict__ x,
                     const float* __restrict__ W,
                     unsigned char* __restrict__ hb8,
                     unsigned short* __restrict__ hnc_out) {
  __shared__ float xs[64 * 65];
  __shared__ unsigned short ht[64 * 72];
  int bid = blockIdx.x;

  if (bid >= 1024) {
    // ---- adj quantize part ----
    size_t base = ((size_t)(bid - 1024) * 256 + threadIdx.x) * 16;
    const float4* src = (const float4*)(adj + base);
    float4 q0 = src[0], q1 = src[1], q2 = src[2], q3 = src[3];
    int4 o;
    o.x = pk4_fp8(q0.x * ADJ_SCALE, q0.y * ADJ_SCALE, q0.z * ADJ_SCALE, q0.w * ADJ_SCALE);
    o.y = pk4_fp8(q1.x * ADJ_SCALE, q1.y * ADJ_SCALE, q1.z * ADJ_SCALE, q1.w * ADJ_SCALE);
    o.z = pk4_fp8(q2.x * ADJ_SCALE, q2.y * ADJ_SCALE, q2.z * ADJ_SCALE, q2.w * ADJ_SCALE);
    o.w = pk4_fp8(q3.x * ADJ_SCALE, q3.y * ADJ_SCALE, q3.z * ADJ_SCALE, q3.w * ADJ_SCALE);
    *(int4*)(a8 + base) = o;
    return;
  }

  // ---- layer-0 linear part ----
  int n0 = (bid & 63) * 64, c0 = (bid >> 6) * 64;

  for (int i = threadIdx.x; i < 1024; i += 256) {
    int bs = i >> 8, rem = i & 255, nr = rem >> 2, d4 = rem & 3;
    float4 v = *(const float4*)(
        x + ((size_t)(c0 / 16 + bs) * 4096 + n0 + nr) * 16 + d4 * 4);
    float* dst = xs + nr * 65 + bs * 16 + d4 * 4;
    dst[0] = v.x; dst[1] = v.y; dst[2] = v.z; dst[3] = v.w;
  }
  __syncthreads();

  int n_l = threadIdx.x & 63, b_l = threadIdx.x >> 6;   // b_l 0..3
  float xv[16];
#pragma unroll
  for (int d = 0; d < 16; ++d) xv[d] = xs[n_l * 65 + b_l * 16 + d];
  float accv[16];
#pragma unroll
  for (int e = 0; e < 16; ++e) accv[e] = 0.f;
#pragma unroll
  for (int d = 0; d < 16; ++d)
#pragma unroll
    for (int e = 0; e < 16; ++e) accv[e] += xv[d] * W[d * 16 + e];

  ushort8 h0, h1;
#pragma unroll
  for (int e = 0; e < 16; ++e) {
    float a = accv[e] > 0.f ? accv[e] : 0.2f * accv[e];
    unsigned short hv = f2bf(a);
    ht[(b_l * 16 + e) * 72 + n_l] = hv;
    if (e < 8) h0[e] = hv; else h1[e - 8] = hv;
  }
  unsigned short* ho = hnc_out + (size_t)(n0 + n_l) * 1024 + c0 + b_l * 16;
  *(ushort8*)(ho)     = h0;
  *(ushort8*)(ho + 8) = h1;
  __syncthreads();

  for (int i = threadIdx.x; i < 512; i += 256) {
    int row = i >> 3, ch = i & 7;
    const unsigned short* s = ht + row * 72 + ch * 8;
    int2 v;
    v.x = pk4_fp8(bf2f(s[0]), bf2f(s[1]), bf2f(s[2]), bf2f(s[3]));
    v.y = pk4_fp8(bf2f(s[4]), bf2f(s[5]), bf2f(s[6]), bf2f(s[7]));
    *(int2*)(hb8 + (size_t)(c0 + row) * 4096 + n0 + ch * 8) = v;
  }
}

// ---------------------------------------------------------------------------
// linear layers 1,2: u = p0 + p1 + h_nc (bf16); h = leaky_relu(u @ W);
// writes hb8 fp8 [c][n] (GEMM B operand, via LDS transpose) and h_nc bf16
// [n][c] (identity term for consumers).  Tile 64n x 64c, grid (64,16).
// ---------------------------------------------------------------------------
__global__ void linear_fuse(const unsigned short* __restrict__ pp,
                            const unsigned short* __restrict__ hnc_in,
                            const float* __restrict__ W,
                            unsigned char* __restrict__ hb8,
                            unsigned short* __restrict__ hnc_out) {
  __shared__ float xs[64 * 65];
  __shared__ unsigned short ht[64 * 72];
  int n0 = blockIdx.x * 64, c0 = blockIdx.y * 64;

  for (int i = threadIdx.x; i < 512; i += 256) {
    int row = i >> 3, ch = i & 7;
    size_t g = (size_t)(n0 + row) * 1024 + c0 + ch * 8;
    ushort8 a = *(const ushort8*)(pp + g);
    ushort8 b = *(const ushort8*)(pp + P_ELEMS + g);
    ushort8 c = *(const ushort8*)(hnc_in + g);
    float* dst = xs + row * 65 + ch * 8;
#pragma unroll
    for (int j = 0; j < 8; ++j) dst[j] = bf2f(a[j]) + bf2f(b[j]) + bf2f(c[j]);
  }
  __syncthreads();

  int n_l = threadIdx.x & 63, b_l = threadIdx.x >> 6;
  float xv[16];
#pragma unroll
  for (int d = 0; d < 16; ++d) xv[d] = xs[n_l * 65 + b_l * 16 + d];
  float accv[16];
#pragma unroll
  for (int e = 0; e < 16; ++e) accv[e] = 0.f;
#pragma unroll
  for (int d = 0; d < 16; ++d)
#pragma unroll
    for (int e = 0; e < 16; ++e) accv[e] += xv[d] * W[d * 16 + e];

  ushort8 h0, h1;
#pragma unroll
  for (int e = 0; e < 16; ++e) {
    float a = accv[e] > 0.f ? accv[e] : 0.2f * accv[e];
    unsigned short hv = f2bf(a);
    ht[(b_l * 16 + e) * 72 + n_l] = hv;
    if (e < 8) h0[e] = hv; else h1[e - 8] = hv;
  }
  unsigned short* ho = hnc_out + (size_t)(n0 + n_l) * 1024 + c0 + b_l * 16;
  *(ushort8*)(ho)     = h0;
  *(ushort8*)(ho + 8) = h1;
  __syncthreads();

  for (int i = threadIdx.x; i < 512; i += 256) {
    int row = i >> 3, ch = i & 7;
    const unsigned short* s = ht + row * 72 + ch * 8;
    int2 v;
    v.x = pk4_fp8(bf2f(s[0]), bf2f(s[1]), bf2f(s[2]), bf2f(s[3]));
    v.y = pk4_fp8(bf2f(s[4]), bf2f(s[5]), bf2f(s[6]), bf2f(s[7]));
    *(int2*)(hb8 + (size_t)(c0 + row) * 4096 + n0 + ch * 8) = v;
  }
}

// ---------------------------------------------------------------------------
// final: out fp32 (b,n,d) = p0 + p1 + h_nc   (all stored [n][c] bf16)
// ---------------------------------------------------------------------------
__global__ void add_out(const unsigned short* __restrict__ pp,
                        const unsigned short* __restrict__ hnc,
                        float* __restrict__ out) {
  int gid = blockIdx.x * 256 + threadIdx.x;      // 0..524287
  int n = gid >> 7, c8 = (gid & 127) * 8;
  size_t g = (size_t)n * 1024 + c8;
  ushort8 a = *(const ushort8*)(pp + g);
  ushort8 b = *(const ushort8*)(pp + P_ELEMS + g);
  ushort8 h = *(const ushort8*)(hnc + g);
  float v[8];
#pragma unroll
  for (int j = 0; j < 8; ++j) v[j] = bf2f(a[j]) + bf2f(b[j]) + bf2f(h[j]);
  int bb = c8 >> 4, d0 = c8 & 15;                // d0 = 0 or 8
  float* o = out + (size_t)bb * 65536 + n * 16 + d0;
  *(float4*)(o)     = float4{v[0], v[1], v[2], v[3]};
  *(float4*)(o + 4) = float4{v[4], v[5], v[6], v[7]};
}

// ---------------------------------------------------------------------------
// p[ks][n][c] = (adj8[n0..][k] * hb8[c0..][k]) / 4096   (one K-half per block)
// MX-scaled fp8 MFMA 16x16x128, unit scales.  Grid 512 = 32mt x 8ct x 2ks,
// xcd = mt&7, 4 waves 2x2, wave tile 64x64.
// A: LDS double-buffered, XOR swizzle phys_chunk = logical ^ (row&7), staged
//    with global_load_lds AFTER the barrier -> drained at the NEXT barrier
//    (latency hidden under 16 MFMAs).  One barrier per iter.
// B: direct global->register (hb8 L2-hot, 4 MB).  Per lane 32 B contiguous
//    at row*K + k0 + q*32 = logical chunks {2q,2q+1} -> same bytes the LDS
//    path delivered; bit-identical contraction.
// Per CU-iter: LDS 48 KB (768 cyc) | L2 64 KB (~490 cyc) | MFMA 1106 cyc.
// ---------------------------------------------------------------------------
__global__ __launch_bounds__(256, 2)
void gemm_f8(const unsigned char* __restrict__ A,
             const unsigned char* __restrict__ B8,
             unsigned short* __restrict__ pp) {
  const int K = 4096;
  __shared__ unsigned char a_s[2][128 * 128];   // 2 x 16 KB

  int tid = threadIdx.x, wave = tid >> 6, lane = tid & 63;

  int lin = blockIdx.x;
  int xcd = lin & 7, g = lin >> 3;
  int mth = g & 3, ct = (g >> 2) & 7, ks = g >> 5;   // ks in {0,1}
  int mt = mth * 8 + xcd;
  int n0 = mt * 128, c0 = ct * 128;
  int kbase = ks * 2048;

  // A staging: wave w covers rows w*32..w*32+31 (4 insts)
  int l8 = lane >> 3, lc = lane & 7;
  int swc = lc ^ l8;                 // logical chunk fetched into phys lc
  const unsigned char* gA[4];
#pragma unroll
  for (int j = 0; j < 4; ++j) {
    int r = wave * 32 + j * 8 + l8;
    gA[j] = A + (size_t)(n0 + r) * K + kbase + swc * 16;
  }

  int i16 = lane & 15, q = lane >> 4;
  int wm = wave >> 1, wn = wave & 1;
  int sw7 = i16 & 7;
  int pc0 = ((2 * q) ^ sw7) * 16;        // phys offset of logical chunk 2q
  int pc1 = ((2 * q + 1) ^ sw7) * 16;    // phys offset of logical chunk 2q+1

  // B direct-load pointers: per u-tile, 32 B contiguous per lane
  const unsigned char* gB[4];
#pragma unroll
  for (int u = 0; u < 4; ++u)
    gB[u] = B8 + (size_t)(c0 + wn * 64 + u * 16 + i16) * K + kbase + q * 32;

#define STAGE_A(buf, k0)                                              \
  do {                                                                \
    _Pragma("unroll")                                                 \
    for (int j = 0; j < 4; ++j)                                       \
      GLOAD_LDS16(gA[j] + (k0), a_s[buf] + (wave * 32 + j * 8) * 128);\
  } while (0)

#define LOAD_B(dst, k0)                                               \
  do {                                                                \
    _Pragma("unroll")                                                 \
    for (int u = 0; u < 4; ++u) {                                     \
      const unsigned char* p = gB[u] + (k0);                          \
      i32x4 lo = *(const i32x4*)p;                                    \
      i32x4 hi = *(const i32x4*)(p + 16);                             \
      dst[u] = __builtin_shufflevector(lo, hi, 0, 1, 2, 3, 4, 5, 6, 7); \
    }                                                                 \
  } while (0)

#define COMPUTE(buf, bb)                                              \
  do {                                                                \
    _Pragma("unroll")                                                 \
    for (int t = 0; t < 4; ++t) {                                     \
      const unsigned char* ap = a_s[buf] + (wm * 64 + t * 16 + i16) * 128; \
      i32x4 alo = *(const i32x4*)(ap + pc0);                          \
      i32x4 ahi = *(const i32x4*)(ap + pc1);                          \
      i32x8 av = __builtin_shufflevector(alo, ahi, 0, 1, 2, 3, 4, 5, 6, 7); \
      _Pragma("unroll")                                               \
      for (int u = 0; u < 4; ++u)                                     \
        acc[t][u] = __builtin_amdgcn_mfma_scale_f32_16x16x128_f8f6f4( \
            av, bb[u], acc[t][u], 0, 0, 0, SCALE_ONE, 0, SCALE_ONE);  \
    }                                                                 \
  } while (0)

  f32x4 acc[4][4] = {};
  i32x8 b0[4], b1[4];

  // prologue: tile 0 in flight
  STAGE_A(0, 0);
  LOAD_B(b0, 0);

  for (int it = 0; it < 16; it += 2) {
    __syncthreads();                     // a_s[0] + b0 ready (drained here)
    STAGE_A(1, (it + 1) * 128);          // it+1 <= 15 always
    LOAD_B(b1, (it + 1) * 128);
    COMPUTE(0, b0);                      // overlaps the it+1 loads

    __syncthreads();                     // a_s[1] + b1 ready
    if (it + 2 < 16) {
      STAGE_A(0, (it + 2) * 128);
      LOAD_B(b0, (it + 2) * 128);
    }
    COMPUTE(1, b1);
  }

#undef STAGE_A
#undef LOAD_B
#undef COMPUTE

  // epilogue: descale + bf16 store of this K-half's partial
  unsigned short* dst = pp + (size_t)ks * P_ELEMS;
#pragma unroll
  for (int t = 0; t < 4; ++t)
#pragma unroll
    for (int u = 0; u < 4; ++u)
#pragma unroll
      for (int i = 0; i < 4; ++i) {
        int n_g = n0 + wm * 64 + t * 16 + q * 4 + i;
        int c_g = c0 + wn * 64 + u * 16 + i16;
        dst[(size_t)n_g * 1024 + c_g] = f2bf(acc[t][u][i] * ADJ_DESCALE);
      }
}

// ---------------------------------------------------------------------------
extern "C" void kernel_launch(void* const* d_in, const int* in_sizes, int n_in,
                              void* d_out, int out_size, void* d_ws, size_t ws_size,
                              hipStream_t stream) {
  const float* x   = (const float*)d_in[0];
  const float* adj = (const float*)d_in[1];
  // d_in[2] = Identity (handled as the +h_nc term)
  const float* W0  = (const float*)d_in[3];
  const float* W1  = (const float*)d_in[4];
  const float* W2  = (const float*)d_in[5];
  float* out = (float*)d_out;

  char* ws = (char*)d_ws;
  unsigned char*  adj8 = (unsigned char*)ws;                   // 16 MiB
  unsigned char*  hb8  = (unsigned char*)(ws + 16777216);      //  4 MiB
  unsigned short* hnc  = (unsigned short*)(ws + 20971520);     //  8 MiB
  unsigned short* pp   = (unsigned short*)(ws + 29360128);     // p0|p1 16 MiB

  // layer 0 linear + adj quantize fused (independent, both memory-bound)
  prep<<<5120, 256, 0, stream>>>(adj, adj8, x, W0, hb8, hnc);
  gemm_f8<<<512, 256, 0, stream>>>(adj8, hb8, pp);
  // layer 1
  linear_fuse<<<dim3(64, 16), 256, 0, stream>>>(pp, hnc, W1, hb8, hnc);
  gemm_f8<<<512, 256, 0, stream>>>(adj8, hb8, pp);
  // layer 2
  linear_fuse<<<dim3(64, 16), 256, 0, stream>>>(pp, hnc, W2, hb8, hnc);
  gemm_f8<<<512, 256, 0, stream>>>(adj8, hb8, pp);
  add_out<<<2048, 256, 0, stream>>>(pp, hnc, out);
}

// Round 3
// 246.861 us; speedup vs baseline: 1.2077x; 1.2077x over previous
//
#include <hip/hip_runtime.h>
#include <stdint.h>

// ---------------------------------------------------------------------------
// GCN block: 3 x [ h = leaky_relu(in @ W);  out = adj@h + h ]   (I folded OUT)
// B=64, N=4096, D=16.  GEMM M=4096 x C=1024 x K=4096 in FP8 e4m3, fp32 accum,
// MX-scaled mfma_scale_16x16x128 with unit scales (2.26x fp8 pipe rate).
// Round 9: r8's B-direct-from-L2 regressed (L2 dup traffic + L3 latency
// exposed at the barrier: MfmaUtil 14%, hbm 1 TB/s -> latency-bound).
// Revert to r7's LDS staging for BOTH operands (proven conflict-free XOR
// swizzle, unique-bytes-once), keep r8's double-buffer schedule:
//   STAGE(next) issued post-barrier -> COMPUTE(cur) ~1100-1536 cyc ->
//   one __syncthreads (vmcnt0 drain) per K-tile.  Load latency hides under
//   compute.  LDS 2x(A16K+B16K)=64KB/block, 2 blocks/CU = 128KB <= 160KB.
// Floor: max(LDS port 1536, MFMA 1106) cyc/CU-iter -> ~10.2us/gemm.
// ws: adj8 16MB | hb8 4MB | h_nc 8MB | p0 8MB | p1 8MB = 44MB
// ---------------------------------------------------------------------------

typedef float  f32x4  __attribute__((ext_vector_type(4)));
typedef unsigned short ushort8 __attribute__((ext_vector_type(8)));
typedef int    i32x4  __attribute__((ext_vector_type(4)));
typedef int    i32x8  __attribute__((ext_vector_type(8)));

typedef __attribute__((address_space(1))) void* as1p;
typedef __attribute__((address_space(3))) void* as3p;
#define GLOAD_LDS16(G, L) \
  __builtin_amdgcn_global_load_lds((as1p)(G), (as3p)(L), 16, 0, 0)

#define P_ELEMS 4194304       // elems per partial buffer (4096*1024)
#define ADJ_SCALE 4096.0f
#define ADJ_DESCALE (1.0f / 4096.0f)
#define SCALE_ONE 0x7f7f7f7f  // e8m0 exponent 127 = 2^0 = 1.0 in every byte

__device__ __forceinline__ unsigned short f2bf(float f) {
  unsigned u = __float_as_uint(f);
  u += 0x7fffu + ((u >> 16) & 1u);  // RNE
  return (unsigned short)(u >> 16);
}
__device__ __forceinline__ float bf2f(unsigned short u) {
  return __uint_as_float(((unsigned)u) << 16);
}
// pack 4 fp32 -> 4 fp8 e4m3 bytes (RNE, saturating)
__device__ __forceinline__ int pk4_fp8(float a, float b, float c, float d) {
  int v = __builtin_amdgcn_cvt_pk_fp8_f32(a, b, 0, false);   // bytes 0,1
  v = __builtin_amdgcn_cvt_pk_fp8_f32(c, d, v, true);        // bytes 2,3
  return v;
}

// ---------------------------------------------------------------------------
// prep: role-split fusion of two independent memory-bound kernels.
//   bid <  1024 : layer-0 linear  h0 = leaky(x @ W0), tile 64n x 64c
//   bid >= 1024 : adj8 = e4m3(adj * 4096), 1 thread = 16 elements
// ---------------------------------------------------------------------------
__global__ void prep(const float* __restrict__ adj,
                     unsigned char* __restrict__ a8,
                     const float* __restrict__ x,
                     const float* __restrict__ W,
                     unsigned char* __restrict__ hb8,
                     unsigned short* __restrict__ hnc_out) {
  __shared__ float xs[64 * 65];
  __shared__ unsigned short ht[64 * 72];
  int bid = blockIdx.x;

  if (bid >= 1024) {
    // ---- adj quantize part ----
    size_t base = ((size_t)(bid - 1024) * 256 + threadIdx.x) * 16;
    const float4* src = (const float4*)(adj + base);
    float4 q0 = src[0], q1 = src[1], q2 = src[2], q3 = src[3];
    int4 o;
    o.x = pk4_fp8(q0.x * ADJ_SCALE, q0.y * ADJ_SCALE, q0.z * ADJ_SCALE, q0.w * ADJ_SCALE);
    o.y = pk4_fp8(q1.x * ADJ_SCALE, q1.y * ADJ_SCALE, q1.z * ADJ_SCALE, q1.w * ADJ_SCALE);
    o.z = pk4_fp8(q2.x * ADJ_SCALE, q2.y * ADJ_SCALE, q2.z * ADJ_SCALE, q2.w * ADJ_SCALE);
    o.w = pk4_fp8(q3.x * ADJ_SCALE, q3.y * ADJ_SCALE, q3.z * ADJ_SCALE, q3.w * ADJ_SCALE);
    *(int4*)(a8 + base) = o;
    return;
  }

  // ---- layer-0 linear part ----
  int n0 = (bid & 63) * 64, c0 = (bid >> 6) * 64;

  for (int i = threadIdx.x; i < 1024; i += 256) {
    int bs = i >> 8, rem = i & 255, nr = rem >> 2, d4 = rem & 3;
    float4 v = *(const float4*)(
        x + ((size_t)(c0 / 16 + bs) * 4096 + n0 + nr) * 16 + d4 * 4);
    float* dst = xs + nr * 65 + bs * 16 + d4 * 4;
    dst[0] = v.x; dst[1] = v.y; dst[2] = v.z; dst[3] = v.w;
  }
  __syncthreads();

  int n_l = threadIdx.x & 63, b_l = threadIdx.x >> 6;   // b_l 0..3
  float xv[16];
#pragma unroll
  for (int d = 0; d < 16; ++d) xv[d] = xs[n_l * 65 + b_l * 16 + d];
  float accv[16];
#pragma unroll
  for (int e = 0; e < 16; ++e) accv[e] = 0.f;
#pragma unroll
  for (int d = 0; d < 16; ++d)
#pragma unroll
    for (int e = 0; e < 16; ++e) accv[e] += xv[d] * W[d * 16 + e];

  ushort8 h0, h1;
#pragma unroll
  for (int e = 0; e < 16; ++e) {
    float a = accv[e] > 0.f ? accv[e] : 0.2f * accv[e];
    unsigned short hv = f2bf(a);
    ht[(b_l * 16 + e) * 72 + n_l] = hv;
    if (e < 8) h0[e] = hv; else h1[e - 8] = hv;
  }
  unsigned short* ho = hnc_out + (size_t)(n0 + n_l) * 1024 + c0 + b_l * 16;
  *(ushort8*)(ho)     = h0;
  *(ushort8*)(ho + 8) = h1;
  __syncthreads();

  for (int i = threadIdx.x; i < 512; i += 256) {
    int row = i >> 3, ch = i & 7;
    const unsigned short* s = ht + row * 72 + ch * 8;
    int2 v;
    v.x = pk4_fp8(bf2f(s[0]), bf2f(s[1]), bf2f(s[2]), bf2f(s[3]));
    v.y = pk4_fp8(bf2f(s[4]), bf2f(s[5]), bf2f(s[6]), bf2f(s[7]));
    *(int2*)(hb8 + (size_t)(c0 + row) * 4096 + n0 + ch * 8) = v;
  }
}

// ---------------------------------------------------------------------------
// linear layers 1,2: u = p0 + p1 + h_nc (bf16); h = leaky_relu(u @ W);
// writes hb8 fp8 [c][n] (GEMM B operand, via LDS transpose) and h_nc bf16
// [n][c] (identity term for consumers).  Tile 64n x 64c, grid (64,16).
// ---------------------------------------------------------------------------
__global__ void linear_fuse(const unsigned short* __restrict__ pp,
                            const unsigned short* __restrict__ hnc_in,
                            const float* __restrict__ W,
                            unsigned char* __restrict__ hb8,
                            unsigned short* __restrict__ hnc_out) {
  __shared__ float xs[64 * 65];
  __shared__ unsigned short ht[64 * 72];
  int n0 = blockIdx.x * 64, c0 = blockIdx.y * 64;

  for (int i = threadIdx.x; i < 512; i += 256) {
    int row = i >> 3, ch = i & 7;
    size_t g = (size_t)(n0 + row) * 1024 + c0 + ch * 8;
    ushort8 a = *(const ushort8*)(pp + g);
    ushort8 b = *(const ushort8*)(pp + P_ELEMS + g);
    ushort8 c = *(const ushort8*)(hnc_in + g);
    float* dst = xs + row * 65 + ch * 8;
#pragma unroll
    for (int j = 0; j < 8; ++j) dst[j] = bf2f(a[j]) + bf2f(b[j]) + bf2f(c[j]);
  }
  __syncthreads();

  int n_l = threadIdx.x & 63, b_l = threadIdx.x >> 6;
  float xv[16];
#pragma unroll
  for (int d = 0; d < 16; ++d) xv[d] = xs[n_l * 65 + b_l * 16 + d];
  float accv[16];
#pragma unroll
  for (int e = 0; e < 16; ++e) accv[e] = 0.f;
#pragma unroll
  for (int d = 0; d < 16; ++d)
#pragma unroll
    for (int e = 0; e < 16; ++e) accv[e] += xv[d] * W[d * 16 + e];

  ushort8 h0, h1;
#pragma unroll
  for (int e = 0; e < 16; ++e) {
    float a = accv[e] > 0.f ? accv[e] : 0.2f * accv[e];
    unsigned short hv = f2bf(a);
    ht[(b_l * 16 + e) * 72 + n_l] = hv;
    if (e < 8) h0[e] = hv; else h1[e - 8] = hv;
  }
  unsigned short* ho = hnc_out + (size_t)(n0 + n_l) * 1024 + c0 + b_l * 16;
  *(ushort8*)(ho)     = h0;
  *(ushort8*)(ho + 8) = h1;
  __syncthreads();

  for (int i = threadIdx.x; i < 512; i += 256) {
    int row = i >> 3, ch = i & 7;
    const unsigned short* s = ht + row * 72 + ch * 8;
    int2 v;
    v.x = pk4_fp8(bf2f(s[0]), bf2f(s[1]), bf2f(s[2]), bf2f(s[3]));
    v.y = pk4_fp8(bf2f(s[4]), bf2f(s[5]), bf2f(s[6]), bf2f(s[7]));
    *(int2*)(hb8 + (size_t)(c0 + row) * 4096 + n0 + ch * 8) = v;
  }
}

// ---------------------------------------------------------------------------
// final: out fp32 (b,n,d) = p0 + p1 + h_nc   (all stored [n][c] bf16)
// ---------------------------------------------------------------------------
__global__ void add_out(const unsigned short* __restrict__ pp,
                        const unsigned short* __restrict__ hnc,
                        float* __restrict__ out) {
  int gid = blockIdx.x * 256 + threadIdx.x;      // 0..524287
  int n = gid >> 7, c8 = (gid & 127) * 8;
  size_t g = (size_t)n * 1024 + c8;
  ushort8 a = *(const ushort8*)(pp + g);
  ushort8 b = *(const ushort8*)(pp + P_ELEMS + g);
  ushort8 h = *(const ushort8*)(hnc + g);
  float v[8];
#pragma unroll
  for (int j = 0; j < 8; ++j) v[j] = bf2f(a[j]) + bf2f(b[j]) + bf2f(h[j]);
  int bb = c8 >> 4, d0 = c8 & 15;                // d0 = 0 or 8
  float* o = out + (size_t)bb * 65536 + n * 16 + d0;
  *(float4*)(o)     = float4{v[0], v[1], v[2], v[3]};
  *(float4*)(o + 4) = float4{v[4], v[5], v[6], v[7]};
}

// ---------------------------------------------------------------------------
// p[ks][n][c] = (adj8[n0..][k] * hb8[c0..][k]) / 4096   (one K-half per block)
// MX-scaled fp8 MFMA 16x16x128, unit scales.  Grid 512 = 32mt x 8ct x 2ks,
// xcd = mt&7, 4 waves 2x2, wave tile 64x64.
// Both A and B staged via global_load_lds, XOR swizzle phys_chunk =
// logical ^ (row&7), DOUBLE-BUFFERED: stage(it+1) issued right after the
// barrier that published tile it, drained by the single __syncthreads
// (vmcnt0) AFTER compute(it) -> load latency hidden under ~1100-1536 cyc
// of ds_read+MFMA.  One barrier per K-tile.
// Lane fragment = 32 B = logical chunks {2q, 2q+1}: positional contraction,
// bit-identical to the non-scaled fp8 path (absmax unchanged).
// Per CU-iter: LDS 2x96KB interleaved -> 1536 cyc wall | MFMA 1106 cyc.
// ---------------------------------------------------------------------------
__global__ __launch_bounds__(256, 2)
void gemm_f8(const unsigned char* __restrict__ A,
             const unsigned char* __restrict__ B8,
             unsigned short* __restrict__ pp) {
  const int K = 4096;
  __shared__ unsigned char a_s[2][128 * 128];   // 2 x 16 KB
  __shared__ unsigned char b_s[2][128 * 128];   // 2 x 16 KB

  int tid = threadIdx.x, wave = tid >> 6, lane = tid & 63;

  int lin = blockIdx.x;
  int xcd = lin & 7, g = lin >> 3;
  int mth = g & 3, ct = (g >> 2) & 7, ks = g >> 5;   // ks in {0,1}
  int mt = mth * 8 + xcd;
  int n0 = mt * 128, c0 = ct * 128;
  int kbase = ks * 2048;

  // staging: wave w covers rows w*32..w*32+31 (4 insts each operand)
  int l8 = lane >> 3, lc = lane & 7;
  int swc = lc ^ l8;                 // logical chunk fetched into phys lc
  const unsigned char* gA[4];
  const unsigned char* gB[4];
#pragma unroll
  for (int j = 0; j < 4; ++j) {
    int r = wave * 32 + j * 8 + l8;
    gA[j] = A  + (size_t)(n0 + r) * K + kbase + swc * 16;
    gB[j] = B8 + (size_t)(c0 + r) * K + kbase + swc * 16;
  }

  int i16 = lane & 15, q = lane >> 4;
  int wm = wave >> 1, wn = wave & 1;
  int sw7 = i16 & 7;
  int pc0 = ((2 * q) ^ sw7) * 16;        // phys offset of logical chunk 2q
  int pc1 = ((2 * q + 1) ^ sw7) * 16;    // phys offset of logical chunk 2q+1

#define STAGE(buf, k0)                                                \
  do {                                                                \
    _Pragma("unroll")                                                 \
    for (int j = 0; j < 4; ++j) {                                     \
      GLOAD_LDS16(gA[j] + (k0), a_s[buf] + (wave * 32 + j * 8) * 128);\
      GLOAD_LDS16(gB[j] + (k0), b_s[buf] + (wave * 32 + j * 8) * 128);\
    }                                                                 \
  } while (0)

#define COMPUTE(buf)                                                  \
  do {                                                                \
    i32x8 bv[4];                                                      \
    _Pragma("unroll")                                                 \
    for (int u = 0; u < 4; ++u) {                                     \
      const unsigned char* bp = b_s[buf] + (wn * 64 + u * 16 + i16) * 128; \
      i32x4 blo = *(const i32x4*)(bp + pc0);                          \
      i32x4 bhi = *(const i32x4*)(bp + pc1);                          \
      bv[u] = __builtin_shufflevector(blo, bhi, 0, 1, 2, 3, 4, 5, 6, 7); \
    }                                                                 \
    _Pragma("unroll")                                                 \
    for (int t = 0; t < 4; ++t) {                                     \
      const unsigned char* ap = a_s[buf] + (wm * 64 + t * 16 + i16) * 128; \
      i32x4 alo = *(const i32x4*)(ap + pc0);                          \
      i32x4 ahi = *(const i32x4*)(ap + pc1);                          \
      i32x8 av = __builtin_shufflevector(alo, ahi, 0, 1, 2, 3, 4, 5, 6, 7); \
      _Pragma("unroll")                                               \
      for (int u = 0; u < 4; ++u)                                     \
        acc[t][u] = __builtin_amdgcn_mfma_scale_f32_16x16x128_f8f6f4( \
            av, bv[u], acc[t][u], 0, 0, 0, SCALE_ONE, 0, SCALE_ONE);  \
    }                                                                 \
  } while (0)

  f32x4 acc[4][4] = {};

  // prologue: tile 0 staged, drained once (startup latency, unhidden)
  STAGE(0, 0);
  __syncthreads();

  for (int it = 0; it < 16; it += 2) {
    STAGE(1, (it + 1) * 128);            // it+1 <= 15 always
    COMPUTE(0);                          // overlaps stage(it+1) latency
    __syncthreads();                     // drains stage(1); reads of buf0 done

    if (it + 2 < 16) STAGE(0, (it + 2) * 128);
    COMPUTE(1);
    __syncthreads();                     // drains stage(0); reads of buf1 done
  }

#undef STAGE
#undef COMPUTE

  // epilogue: descale + bf16 store of this K-half's partial
  unsigned short* dst = pp + (size_t)ks * P_ELEMS;
#pragma unroll
  for (int t = 0; t < 4; ++t)
#pragma unroll
    for (int u = 0; u < 4; ++u)
#pragma unroll
      for (int i = 0; i < 4; ++i) {
        int n_g = n0 + wm * 64 + t * 16 + q * 4 + i;
        int c_g = c0 + wn * 64 + u * 16 + i16;
        dst[(size_t)n_g * 1024 + c_g] = f2bf(acc[t][u][i] * ADJ_DESCALE);
      }
}

// ---------------------------------------------------------------------------
extern "C" void kernel_launch(void* const* d_in, const int* in_sizes, int n_in,
                              void* d_out, int out_size, void* d_ws, size_t ws_size,
                              hipStream_t stream) {
  const float* x   = (const float*)d_in[0];
  const float* adj = (const float*)d_in[1];
  // d_in[2] = Identity (handled as the +h_nc term)
  const float* W0  = (const float*)d_in[3];
  const float* W1  = (const float*)d_in[4];
  const float* W2  = (const float*)d_in[5];
  float* out = (float*)d_out;

  char* ws = (char*)d_ws;
  unsigned char*  adj8 = (unsigned char*)ws;                   // 16 MiB
  unsigned char*  hb8  = (unsigned char*)(ws + 16777216);      //  4 MiB
  unsigned short* hnc  = (unsigned short*)(ws + 20971520);     //  8 MiB
  unsigned short* pp   = (unsigned short*)(ws + 29360128);     // p0|p1 16 MiB

  // layer 0 linear + adj quantize fused (independent, both memory-bound)
  prep<<<5120, 256, 0, stream>>>(adj, adj8, x, W0, hb8, hnc);
  gemm_f8<<<512, 256, 0, stream>>>(adj8, hb8, pp);
  // layer 1
  linear_fuse<<<dim3(64, 16), 256, 0, stream>>>(pp, hnc, W1, hb8, hnc);
  gemm_f8<<<512, 256, 0, stream>>>(adj8, hb8, pp);
  // layer 2
  linear_fuse<<<dim3(64, 16), 256, 0, stream>>>(pp, hnc, W2, hb8, hnc);
  gemm_f8<<<512, 256, 0, stream>>>(adj8, hb8, pp);
  add_out<<<2048, 256, 0, stream>>>(pp, hnc, out);
}